// Round 1
// baseline (387.078 us; speedup 1.0000x reference)
//
#include <hip/hip_runtime.h>
#include <hip/hip_bf16.h>

typedef __bf16 bf16x8 __attribute__((ext_vector_type(8)));
typedef float  f32x4  __attribute__((ext_vector_type(4)));
typedef unsigned short u16;

// fp32 -> bf16 RNE via native cvt
__device__ __forceinline__ u16 f2bf(float f) {
    __bf16 h = (__bf16)f;
    return __builtin_bit_cast(u16, h);
}

__device__ __forceinline__ f32x4 mfma16(bf16x8 a, bf16x8 b, f32x4 c) {
    return __builtin_amdgcn_mfma_f32_16x16x32_bf16(a, b, c, 0, 0, 0);
}

// ---------------------------------------------------------------------------
// GEMM: C[m,n] = sum_k A[m,k] * W[n,k]   (torch Linear, no bias)
// M=4096, N=1024, K=1024 hardcoded. A is fp32 (ABF16=false) or bf16 (true).
// W always fp32 [N][K]. CMODE: 0 = bf16 row-major out, 1 = bf16 per-head
// transposed out ([b][h][dk][T], for V), 2 = fp32 row-major out.
// 128x128 tile, BK=32, 256 thr (4 waves), each wave 64x64 via 4x4 MFMA frags.
// ---------------------------------------------------------------------------
template <int CMODE, bool ABF16>
__global__ __launch_bounds__(256) void gemm_xwt(const void* __restrict__ Ap,
                                                const float* __restrict__ W,
                                                void* __restrict__ Cp) {
    constexpr int K = 1024, N = 1024;
    __shared__ u16 As[128 * 32];
    __shared__ u16 Bs[128 * 32];

    const int tid  = threadIdx.x;
    const int lane = tid & 63;
    const int w    = tid >> 6;
    const int wr = w >> 1, wc = w & 1;
    const int m0 = blockIdx.y * 128, n0 = blockIdx.x * 128;
    const int colg = lane & 15, rowg = lane >> 4;

    f32x4 acc[4][4];
#pragma unroll
    for (int i = 0; i < 4; ++i)
#pragma unroll
        for (int j = 0; j < 4; ++j) acc[i][j] = (f32x4){0.f, 0.f, 0.f, 0.f};

    for (int kk = 0; kk < K; kk += 32) {
#pragma unroll
        for (int i = 0; i < 2; ++i) {
            const int c   = i * 256 + tid;      // chunk id, 512 chunks of 8 elems
            const int row = c >> 2;
            const int cg  = (c & 3) * 8;
            // ---- A tile ----
            if constexpr (ABF16) {
                const u16* g = (const u16*)Ap + (size_t)(m0 + row) * K + kk + cg;
                *(uint4*)(&As[c * 8]) = *(const uint4*)g;
            } else {
                const float* g = (const float*)Ap + (size_t)(m0 + row) * K + kk + cg;
                float4 f0 = *(const float4*)g;
                float4 f1 = *(const float4*)(g + 4);
                bf16x8 u;
                u[0] = (__bf16)f0.x; u[1] = (__bf16)f0.y; u[2] = (__bf16)f0.z; u[3] = (__bf16)f0.w;
                u[4] = (__bf16)f1.x; u[5] = (__bf16)f1.y; u[6] = (__bf16)f1.z; u[7] = (__bf16)f1.w;
                *(bf16x8*)(&As[c * 8]) = u;
            }
            // ---- B tile (weights, fp32 [N][K]) ----
            {
                const float* g = W + (size_t)(n0 + row) * K + kk + cg;
                float4 f0 = *(const float4*)g;
                float4 f1 = *(const float4*)(g + 4);
                bf16x8 u;
                u[0] = (__bf16)f0.x; u[1] = (__bf16)f0.y; u[2] = (__bf16)f0.z; u[3] = (__bf16)f0.w;
                u[4] = (__bf16)f1.x; u[5] = (__bf16)f1.y; u[6] = (__bf16)f1.z; u[7] = (__bf16)f1.w;
                *(bf16x8*)(&Bs[c * 8]) = u;
            }
        }
        __syncthreads();

        bf16x8 af[4], bfr[4];
#pragma unroll
        for (int mi = 0; mi < 4; ++mi)
            af[mi] = *(const bf16x8*)(&As[(wr * 64 + mi * 16 + colg) * 32 + rowg * 8]);
#pragma unroll
        for (int ni = 0; ni < 4; ++ni)
            bfr[ni] = *(const bf16x8*)(&Bs[(wc * 64 + ni * 16 + colg) * 32 + rowg * 8]);
#pragma unroll
        for (int mi = 0; mi < 4; ++mi)
#pragma unroll
            for (int ni = 0; ni < 4; ++ni)
                acc[mi][ni] = mfma16(af[mi], bfr[ni], acc[mi][ni]);
        __syncthreads();
    }

    // epilogue: C/D layout col = lane&15, row = (lane>>4)*4 + reg
#pragma unroll
    for (int mi = 0; mi < 4; ++mi) {
#pragma unroll
        for (int ni = 0; ni < 4; ++ni) {
#pragma unroll
            for (int r = 0; r < 4; ++r) {
                const int row = m0 + wr * 64 + mi * 16 + rowg * 4 + r;
                const int col = n0 + wc * 64 + ni * 16 + colg;
                const float v = acc[mi][ni][r];
                if constexpr (CMODE == 0) {
                    ((u16*)Cp)[(size_t)row * N + col] = f2bf(v);
                } else if constexpr (CMODE == 1) {
                    // V transposed per head: Vt[b][h][d][t], T=2048
                    const int b = row >> 11, t = row & 2047;
                    const int h = col >> 6,  d = col & 63;
                    ((u16*)Cp)[((size_t)((b * 16 + h) * 64 + d) << 11) + t] = f2bf(v);
                } else {
                    ((float*)Cp)[(size_t)row * N + col] = v;
                }
            }
        }
    }
}

// ---------------------------------------------------------------------------
// Flash-style causal attention.
// Qp, Kp: bf16 [B*T][C] row-major (per-head cols h*64..h*64+63)
// Vt:     bf16 [B][H][64][T] (per-head transposed)
// concat: bf16 [B*T][C]
// Block: 256 thr = 4 independent waves; wave handles 16 q-rows, KVBLK=32.
// ---------------------------------------------------------------------------
__global__ __launch_bounds__(256) void attn_causal(const u16* __restrict__ Qp,
                                                   const u16* __restrict__ Kp,
                                                   const u16* __restrict__ Vt,
                                                   u16* __restrict__ concat) {
    constexpr int T = 2048, C = 1024;
    __shared__ u16 Plds[4][16 * 32];  // per-wave P tile [q16][kv32]

    const int lane = threadIdx.x & 63;
    const int w    = threadIdx.x >> 6;
    const int q0   = blockIdx.x * 64 + w * 16;
    const int bh   = blockIdx.y;
    const int b = bh >> 4, h = bh & 15;
    const int colg = lane & 15, rowg = lane >> 4;

    // Q A-frags (rows = lane&15, k-chunk = (lane>>4)*8)
    const u16* Qbase = Qp + (size_t)(b * T + q0 + colg) * C + h * 64;
    const bf16x8 qf0 = *(const bf16x8*)(Qbase + rowg * 8);
    const bf16x8 qf1 = *(const bf16x8*)(Qbase + 32 + rowg * 8);

    float m[4], l[4];
    f32x4 O[4];
#pragma unroll
    for (int r = 0; r < 4; ++r) { m[r] = -INFINITY; l[r] = 0.f; }
#pragma unroll
    for (int g = 0; g < 4; ++g) O[g] = (f32x4){0.f, 0.f, 0.f, 0.f};

    const u16* Krow  = Kp + (size_t)(b * T) * C + h * 64;
    const u16* Vbase = Vt + ((size_t)(b * 16 + h) * 64) * T;

    const int ntiles = (q0 + 16 + 31) >> 5;
    for (int kt = 0; kt < ntiles; ++kt) {
        const int kvb = kt * 32;
        // S = (Q K^T) for 16q x 32kv, two 16x16 sub-tiles
        float p[2][4];
#pragma unroll
        for (int sub = 0; sub < 2; ++sub) {
            const u16* kr = Krow + (size_t)(kvb + sub * 16 + colg) * C;
            bf16x8 kf0 = *(const bf16x8*)(kr + rowg * 8);
            bf16x8 kf1 = *(const bf16x8*)(kr + 32 + rowg * 8);
            f32x4 t = (f32x4){0.f, 0.f, 0.f, 0.f};
            t = mfma16(qf0, kf0, t);
            t = mfma16(qf1, kf1, t);
#pragma unroll
            for (int r = 0; r < 4; ++r) {
                float v = t[r] * 0.125f;  // 1/sqrt(dk)
                const int qg  = q0 + rowg * 4 + r;
                const int kvg = kvb + sub * 16 + colg;
                if (kvg > qg) v = -1e30f;  // causal mask
                p[sub][r] = v;
            }
        }
        // online softmax, per q-row (reg r), reduce across the 16-lane group
#pragma unroll
        for (int r = 0; r < 4; ++r) {
            float pm = fmaxf(p[0][r], p[1][r]);
#pragma unroll
            for (int x = 1; x < 16; x <<= 1) pm = fmaxf(pm, __shfl_xor(pm, x, 64));
            const float mn = fmaxf(m[r], pm);
            const float sc = __expf(m[r] - mn);
            const float p0 = __expf(p[0][r] - mn);
            const float p1 = __expf(p[1][r] - mn);
            float rs = p0 + p1;
#pragma unroll
            for (int x = 1; x < 16; x <<= 1) rs += __shfl_xor(rs, x, 64);
            l[r] = l[r] * sc + rs;
            m[r] = mn;
            p[0][r] = p0; p[1][r] = p1;
#pragma unroll
            for (int g = 0; g < 4; ++g) O[g][r] *= sc;
        }
        // transpose P through per-wave LDS: Plds[q][kv]
#pragma unroll
        for (int sub = 0; sub < 2; ++sub)
#pragma unroll
            for (int r = 0; r < 4; ++r)
                Plds[w][(rowg * 4 + r) * 32 + sub * 16 + colg] = f2bf(p[sub][r]);
        asm volatile("" ::: "memory");  // keep ds_write before ds_read in program order
        const bf16x8 pf = *(const bf16x8*)(&Plds[w][colg * 32 + rowg * 8]);
        // PV: O[16q x 64d] += P[16q x 32kv] * V[32kv x 64d]
#pragma unroll
        for (int g = 0; g < 4; ++g) {
            const u16* vr = Vbase + (size_t)(g * 16 + colg) * T + kvb;
            bf16x8 vf = *(const bf16x8*)(vr + rowg * 8);
            O[g] = mfma16(pf, vf, O[g]);
        }
    }

    // epilogue: O /= l, write concat bf16
#pragma unroll
    for (int r = 0; r < 4; ++r) {
        const float rc = 1.f / l[r];
        const size_t rbase = (size_t)(b * T + q0 + rowg * 4 + r) * C + h * 64;
#pragma unroll
        for (int g = 0; g < 4; ++g)
            concat[rbase + g * 16 + colg] = f2bf(O[g][r] * rc);
    }
}

// ---------------------------------------------------------------------------
extern "C" void kernel_launch(void* const* d_in, const int* in_sizes, int n_in,
                              void* d_out, int out_size, void* d_ws, size_t ws_size,
                              hipStream_t stream) {
    const float* q  = (const float*)d_in[0];
    const float* k  = (const float*)d_in[1];
    const float* v  = (const float*)d_in[2];
    const float* Wq = (const float*)d_in[3];
    const float* Wk = (const float*)d_in[4];
    const float* Wv = (const float*)d_in[5];
    const float* Wo = (const float*)d_in[6];
    float* out = (float*)d_out;

    constexpr size_t NELEM = (size_t)4096 * 1024;  // B*T x C
    u16* Qp = (u16*)d_ws;
    u16* Kp = Qp + NELEM;
    u16* Vt = Kp + NELEM;
    u16* Cc = Vt + NELEM;

    dim3 gg(8, 32), gb(256);
    gemm_xwt<0, false><<<gg, gb, 0, stream>>>(q, Wq, Qp);
    gemm_xwt<0, false><<<gg, gb, 0, stream>>>(k, Wk, Kp);
    gemm_xwt<1, false><<<gg, gb, 0, stream>>>(v, Wv, Vt);

    dim3 ag(32, 32);
    attn_causal<<<ag, gb, 0, stream>>>(Qp, Kp, Vt, Cc);

    gemm_xwt<2, true><<<gg, gb, 0, stream>>>(Cc, Wo, out);
}

// Round 2
// 254.897 us; speedup vs baseline: 1.5186x; 1.5186x over previous
//
#include <hip/hip_runtime.h>
#include <hip/hip_bf16.h>

typedef __bf16 bf16x8 __attribute__((ext_vector_type(8)));
typedef float  f32x4  __attribute__((ext_vector_type(4)));
typedef unsigned short u16;

__device__ __forceinline__ u16 f2bf(float f) {
    __bf16 h = (__bf16)f;
    return __builtin_bit_cast(u16, h);
}

__device__ __forceinline__ f32x4 mfma16(bf16x8 a, bf16x8 b, f32x4 c) {
    return __builtin_amdgcn_mfma_f32_16x16x32_bf16(a, b, c, 0, 0, 0);
}

// ---------------------------------------------------------------------------
// Weight pre-conversion: 4 x [1M] fp32 -> bf16, concatenated into dst.
// ---------------------------------------------------------------------------
__global__ __launch_bounds__(256) void cvt4(const float* __restrict__ W0,
                                            const float* __restrict__ W1,
                                            const float* __restrict__ W2,
                                            const float* __restrict__ W3,
                                            u16* __restrict__ dst) {
    const int t     = blockIdx.x * 256 + threadIdx.x;   // 0..512K-1
    const int which = t >> 17;                          // 128K threads per W
    const int off   = (t & 0x1FFFF) * 8;
    const float* s  = (which == 0) ? W0 : (which == 1) ? W1 : (which == 2) ? W2 : W3;
    float4 f0 = *(const float4*)(s + off);
    float4 f1 = *(const float4*)(s + off + 4);
    bf16x8 u;
    u[0] = (__bf16)f0.x; u[1] = (__bf16)f0.y; u[2] = (__bf16)f0.z; u[3] = (__bf16)f0.w;
    u[4] = (__bf16)f1.x; u[5] = (__bf16)f1.y; u[6] = (__bf16)f1.z; u[7] = (__bf16)f1.w;
    *(bf16x8*)(dst + ((size_t)which << 20) + off) = u;
}

// ---------------------------------------------------------------------------
// GEMM: C[m,n] = sum_k A[m,k] * W[n,k]. M=4096, N=1024, K=1024.
// A fp32 (ABF16=false) or bf16 (true); W bf16 [N][K].
// CMODE: 0 = bf16 out, 1 = bf16 per-head transposed ([b][h][dk][T]), 2 = fp32.
// 128x128 tile, BK=32, 256 thr (4 waves). 1-D grid of 256, XCD-swizzled.
// ---------------------------------------------------------------------------
template <int CMODE, bool ABF16>
__global__ __launch_bounds__(256) void gemm_xwt(const void* __restrict__ Ap,
                                                const u16* __restrict__ W,
                                                void* __restrict__ Cp) {
    constexpr int K = 1024, N = 1024;
    __shared__ u16 As[128 * 32];
    __shared__ u16 Bs[128 * 32];

    const int tid  = threadIdx.x;
    const int lane = tid & 63;
    const int w    = tid >> 6;
    const int wr = w >> 1, wc = w & 1;
    // XCD swizzle: 256 blocks, 32 per XCD, group m-strips per XCD
    const int wg = (blockIdx.x & 7) * 32 + (blockIdx.x >> 3);
    const int m0 = (wg >> 3) * 128, n0 = (wg & 7) * 128;
    const int colg = lane & 15, rowg = lane >> 4;

    f32x4 acc[4][4];
#pragma unroll
    for (int i = 0; i < 4; ++i)
#pragma unroll
        for (int j = 0; j < 4; ++j) acc[i][j] = (f32x4){0.f, 0.f, 0.f, 0.f};

    for (int kk = 0; kk < K; kk += 32) {
#pragma unroll
        for (int i = 0; i < 2; ++i) {
            const int c   = i * 256 + tid;      // 512 chunks of 8 elems per tile
            const int row = c >> 2;
            const int cg  = (c & 3) * 8;
            if constexpr (ABF16) {
                const u16* g = (const u16*)Ap + (size_t)(m0 + row) * K + kk + cg;
                *(uint4*)(&As[c * 8]) = *(const uint4*)g;
            } else {
                const float* g = (const float*)Ap + (size_t)(m0 + row) * K + kk + cg;
                float4 f0 = *(const float4*)g;
                float4 f1 = *(const float4*)(g + 4);
                bf16x8 u;
                u[0] = (__bf16)f0.x; u[1] = (__bf16)f0.y; u[2] = (__bf16)f0.z; u[3] = (__bf16)f0.w;
                u[4] = (__bf16)f1.x; u[5] = (__bf16)f1.y; u[6] = (__bf16)f1.z; u[7] = (__bf16)f1.w;
                *(bf16x8*)(&As[c * 8]) = u;
            }
            {
                const u16* g = W + (size_t)(n0 + row) * K + kk + cg;
                *(uint4*)(&Bs[c * 8]) = *(const uint4*)g;
            }
        }
        __syncthreads();

        bf16x8 af[4], bfr[4];
#pragma unroll
        for (int mi = 0; mi < 4; ++mi)
            af[mi] = *(const bf16x8*)(&As[(wr * 64 + mi * 16 + colg) * 32 + rowg * 8]);
#pragma unroll
        for (int ni = 0; ni < 4; ++ni)
            bfr[ni] = *(const bf16x8*)(&Bs[(wc * 64 + ni * 16 + colg) * 32 + rowg * 8]);
#pragma unroll
        for (int mi = 0; mi < 4; ++mi)
#pragma unroll
            for (int ni = 0; ni < 4; ++ni)
                acc[mi][ni] = mfma16(af[mi], bfr[ni], acc[mi][ni]);
        __syncthreads();
    }

#pragma unroll
    for (int mi = 0; mi < 4; ++mi) {
#pragma unroll
        for (int ni = 0; ni < 4; ++ni) {
#pragma unroll
            for (int r = 0; r < 4; ++r) {
                const int row = m0 + wr * 64 + mi * 16 + rowg * 4 + r;
                const int col = n0 + wc * 64 + ni * 16 + colg;
                const float v = acc[mi][ni][r];
                if constexpr (CMODE == 0) {
                    ((u16*)Cp)[(size_t)row * N + col] = f2bf(v);
                } else if constexpr (CMODE == 1) {
                    const int b = row >> 11, t = row & 2047;
                    const int h = col >> 6,  d = col & 63;
                    ((u16*)Cp)[((size_t)((b * 16 + h) * 64 + d) << 11) + t] = f2bf(v);
                } else {
                    ((float*)Cp)[(size_t)row * N + col] = v;
                }
            }
        }
    }
}

// ---------------------------------------------------------------------------
// Flash attention, causal. One wave per block; wave owns q-stripes s and
// 127-s (16 rows each) -> perfectly balanced ~33 KVBLK=64 tiles per wave.
// Qp,Kp: bf16 [B*T][C]; Vt: bf16 [B][H][64][T]; concat: bf16 [B*T][C].
// ---------------------------------------------------------------------------
constexpr float CEXP = 0.18033688011112042f;  // 0.125 * log2(e)

__device__ __forceinline__ void attn_tile(int kvb, int q0, int colg, int rowg,
                                          const u16* __restrict__ Krow,
                                          const u16* __restrict__ Vb,
                                          bf16x8 qf0, bf16x8 qf1,
                                          float (&mm)[4], float (&ll)[4],
                                          f32x4 (&OO)[4], u16* PB) {
    constexpr int T = 2048, C = 1024;
    float pr[4][4];
#pragma unroll
    for (int sub = 0; sub < 4; ++sub) {
        const u16* kr = Krow + (size_t)(kvb + sub * 16 + colg) * C;
        bf16x8 kf0 = *(const bf16x8*)(kr + rowg * 8);
        bf16x8 kf1 = *(const bf16x8*)(kr + 32 + rowg * 8);
        f32x4 t = (f32x4){0.f, 0.f, 0.f, 0.f};
        t = mfma16(qf0, kf0, t);
        t = mfma16(qf1, kf1, t);
#pragma unroll
        for (int r = 0; r < 4; ++r) pr[sub][r] = t[r];
    }
    if (kvb + 63 > q0) {  // wave-uniform: tile touches the diagonal
#pragma unroll
        for (int sub = 0; sub < 4; ++sub)
#pragma unroll
            for (int r = 0; r < 4; ++r) {
                const int qg  = q0 + rowg * 4 + r;
                const int kvg = kvb + sub * 16 + colg;
                if (kvg > qg) pr[sub][r] = -1e30f;
            }
    }
#pragma unroll
    for (int r = 0; r < 4; ++r) {
        float pm = fmaxf(fmaxf(pr[0][r], pr[1][r]), fmaxf(pr[2][r], pr[3][r]));
        pm = fmaxf(pm, __shfl_xor(pm, 1, 64));
        pm = fmaxf(pm, __shfl_xor(pm, 2, 64));
        pm = fmaxf(pm, __shfl_xor(pm, 4, 64));
        pm = fmaxf(pm, __shfl_xor(pm, 8, 64));
        const float mn = fmaxf(mm[r], pm);
        const float sc = __builtin_amdgcn_exp2f((mm[r] - mn) * CEXP);
        mm[r] = mn;
        float rs = 0.f;
#pragma unroll
        for (int sub = 0; sub < 4; ++sub) {
            const float e = __builtin_amdgcn_exp2f((pr[sub][r] - mn) * CEXP);
            pr[sub][r] = e;
            rs += e;
        }
        rs += __shfl_xor(rs, 1, 64);
        rs += __shfl_xor(rs, 2, 64);
        rs += __shfl_xor(rs, 4, 64);
        rs += __shfl_xor(rs, 8, 64);
        ll[r] = ll[r] * sc + rs;
#pragma unroll
        for (int g = 0; g < 4; ++g) OO[g][r] *= sc;
    }
    // P transpose through swizzled LDS: byte = (q*128 + kv*2) ^ ((q&7)<<4)
#pragma unroll
    for (int sub = 0; sub < 4; ++sub)
#pragma unroll
        for (int r = 0; r < 4; ++r) {
            const int qq = rowg * 4 + r;
            const int kv = sub * 16 + colg;
            const int wb = (qq * 128 + kv * 2) ^ ((qq & 7) << 4);
            *(u16*)((char*)PB + wb) = f2bf(pr[sub][r]);
        }
    asm volatile("" ::: "memory");
    const int rb0 = (colg * 128 + rowg * 16) ^ ((colg & 7) << 4);
    const int rb1 = (colg * 128 + 64 + rowg * 16) ^ ((colg & 7) << 4);
    bf16x8 pf0 = *(const bf16x8*)((char*)PB + rb0);
    bf16x8 pf1 = *(const bf16x8*)((char*)PB + rb1);
#pragma unroll
    for (int g = 0; g < 4; ++g) {
        const u16* vr = Vb + (size_t)(g * 16 + colg) * T + kvb;
        bf16x8 v0 = *(const bf16x8*)(vr + rowg * 8);
        bf16x8 v1 = *(const bf16x8*)(vr + 32 + rowg * 8);
        OO[g] = mfma16(pf0, v0, OO[g]);
        OO[g] = mfma16(pf1, v1, OO[g]);
    }
}

__global__ __launch_bounds__(64) void attn_causal(const u16* __restrict__ Qp,
                                                  const u16* __restrict__ Kp,
                                                  const u16* __restrict__ Vt,
                                                  u16* __restrict__ concat) {
    constexpr int T = 2048, C = 1024;
    __shared__ __align__(16) u16 Pl[2][1024];

    const int lane = threadIdx.x;
    const int colg = lane & 15, rowg = lane >> 4;
    // XCD swizzle: 2048 blocks -> 256 consecutive per XCD (4 bh per XCD)
    const int wg = (blockIdx.x & 7) * 256 + (blockIdx.x >> 3);
    const int p  = wg & 63;
    const int bh = wg >> 6;
    const int b = bh >> 4, h = bh & 15;

    const int q0A = p * 16;
    const int q0B = (127 - p) * 16;

    const u16* Krow = Kp + (size_t)(b * T) * C + h * 64;
    const u16* Vb   = Vt + ((size_t)(b * 16 + h) * 64) * T;

    const u16* QA = Qp + (size_t)(b * T + q0A + colg) * C + h * 64;
    const u16* QB = Qp + (size_t)(b * T + q0B + colg) * C + h * 64;
    const bf16x8 qA0 = *(const bf16x8*)(QA + rowg * 8);
    const bf16x8 qA1 = *(const bf16x8*)(QA + 32 + rowg * 8);
    const bf16x8 qB0 = *(const bf16x8*)(QB + rowg * 8);
    const bf16x8 qB1 = *(const bf16x8*)(QB + 32 + rowg * 8);

    float mA[4], lA[4], mB[4], lB[4];
    f32x4 OA[4], OB[4];
#pragma unroll
    for (int r = 0; r < 4; ++r) { mA[r] = -INFINITY; lA[r] = 0.f; mB[r] = -INFINITY; lB[r] = 0.f; }
#pragma unroll
    for (int g = 0; g < 4; ++g) { OA[g] = (f32x4){0.f, 0.f, 0.f, 0.f}; OB[g] = (f32x4){0.f, 0.f, 0.f, 0.f}; }

    const int ntA = (q0A + 79) >> 6;
    const int ntB = (q0B + 79) >> 6;

    for (int kt = 0; kt < ntB; ++kt) {
        const int kvb = kt * 64;
        if (kt < ntA)
            attn_tile(kvb, q0A, colg, rowg, Krow, Vb, qA0, qA1, mA, lA, OA, Pl[0]);
        attn_tile(kvb, q0B, colg, rowg, Krow, Vb, qB0, qB1, mB, lB, OB, Pl[1]);
    }

#pragma unroll
    for (int r = 0; r < 4; ++r) {
        const float rcA = 1.f / lA[r];
        const float rcB = 1.f / lB[r];
        const size_t baseA = (size_t)(b * T + q0A + rowg * 4 + r) * C + h * 64;
        const size_t baseB = (size_t)(b * T + q0B + rowg * 4 + r) * C + h * 64;
#pragma unroll
        for (int g = 0; g < 4; ++g) {
            concat[baseA + g * 16 + colg] = f2bf(OA[g][r] * rcA);
            concat[baseB + g * 16 + colg] = f2bf(OB[g][r] * rcB);
        }
    }
}

// ---------------------------------------------------------------------------
extern "C" void kernel_launch(void* const* d_in, const int* in_sizes, int n_in,
                              void* d_out, int out_size, void* d_ws, size_t ws_size,
                              hipStream_t stream) {
    const float* q  = (const float*)d_in[0];
    const float* k  = (const float*)d_in[1];
    const float* v  = (const float*)d_in[2];
    const float* Wq = (const float*)d_in[3];
    const float* Wk = (const float*)d_in[4];
    const float* Wv = (const float*)d_in[5];
    const float* Wo = (const float*)d_in[6];
    float* out = (float*)d_out;

    constexpr size_t NELEM = (size_t)4096 * 1024;
    constexpr size_t WSZ   = (size_t)1 << 20;
    u16* Wb = (u16*)d_ws;        // 4M bf16 weights
    u16* Qp = Wb + 4 * WSZ;
    u16* Kp = Qp + NELEM;
    u16* Vt = Kp + NELEM;
    u16* Cc = Vt + NELEM;

    cvt4<<<2048, 256, 0, stream>>>(Wq, Wk, Wv, Wo, Wb);

    dim3 gb(256);
    gemm_xwt<0, false><<<256, gb, 0, stream>>>(q, Wb,           Qp);
    gemm_xwt<0, false><<<256, gb, 0, stream>>>(k, Wb + WSZ,     Kp);
    gemm_xwt<1, false><<<256, gb, 0, stream>>>(v, Wb + 2 * WSZ, Vt);

    attn_causal<<<2048, 64, 0, stream>>>(Qp, Kp, Vt, Cc);

    gemm_xwt<2, true><<<256, gb, 0, stream>>>(Cc, Wb + 3 * WSZ, out);
}

// Round 3
// 191.770 us; speedup vs baseline: 2.0185x; 1.3292x over previous
//
#include <hip/hip_runtime.h>
#include <hip/hip_bf16.h>

typedef __bf16 bf16x8 __attribute__((ext_vector_type(8)));
typedef float  f32x4  __attribute__((ext_vector_type(4)));
typedef unsigned short u16;

__device__ __forceinline__ u16 f2bf(float f) {
    __bf16 h = (__bf16)f;
    return __builtin_bit_cast(u16, h);
}

__device__ __forceinline__ f32x4 mfma16(bf16x8 a, bf16x8 b, f32x4 c) {
    return __builtin_amdgcn_mfma_f32_16x16x32_bf16(a, b, c, 0, 0, 0);
}

// ---------------------------------------------------------------------------
// Weight pre-conversion: 4 x [1M] fp32 -> bf16 concatenated.
// ---------------------------------------------------------------------------
__global__ __launch_bounds__(256) void cvt4(const float* __restrict__ W0,
                                            const float* __restrict__ W1,
                                            const float* __restrict__ W2,
                                            const float* __restrict__ W3,
                                            u16* __restrict__ dst) {
    const int t     = blockIdx.x * 256 + threadIdx.x;
    const int which = t >> 17;
    const int off   = (t & 0x1FFFF) * 8;
    const float* s  = (which == 0) ? W0 : (which == 1) ? W1 : (which == 2) ? W2 : W3;
    float4 f0 = *(const float4*)(s + off);
    float4 f1 = *(const float4*)(s + off + 4);
    bf16x8 u;
    u[0] = (__bf16)f0.x; u[1] = (__bf16)f0.y; u[2] = (__bf16)f0.z; u[3] = (__bf16)f0.w;
    u[4] = (__bf16)f1.x; u[5] = (__bf16)f1.y; u[6] = (__bf16)f1.z; u[7] = (__bf16)f1.w;
    *(bf16x8*)(dst + ((size_t)which << 20) + off) = u;
}

// ---------------------------------------------------------------------------
// Merged Q/K/V projection GEMM. 768 blocks (3 x 256 tiles of 128x128).
// A (q,k,v) fp32 [4096][1024]; W bf16. Q,K out row-major bf16; V out
// per-head transposed ([b][h][dk][T]).
// ---------------------------------------------------------------------------
__global__ __launch_bounds__(256) void gemm_qkv(const float* __restrict__ q,
                                                const float* __restrict__ k,
                                                const float* __restrict__ v,
                                                const u16* __restrict__ Wb,
                                                u16* __restrict__ Qp,
                                                u16* __restrict__ Kp,
                                                u16* __restrict__ Vt) {
    constexpr int K = 1024, N = 1024;
    __shared__ u16 As[128 * 32];
    __shared__ u16 Bs[128 * 32];

    const int tid  = threadIdx.x;
    const int lane = tid & 63;
    const int w    = tid >> 6;
    const int wr = w >> 1, wc = w & 1;
    const int wg    = (blockIdx.x & 7) * 96 + (blockIdx.x >> 3);  // XCD swizzle
    const int which = wg >> 8;
    const int inner = wg & 255;
    const int m0 = (inner >> 3) * 128, n0 = (inner & 7) * 128;
    const int colg = lane & 15, rowg = lane >> 4;

    const float* A = (which == 0) ? q : (which == 1) ? k : v;
    const u16*   W = Wb + ((size_t)which << 20);

    f32x4 acc[4][4];
#pragma unroll
    for (int i = 0; i < 4; ++i)
#pragma unroll
        for (int j = 0; j < 4; ++j) acc[i][j] = (f32x4){0.f, 0.f, 0.f, 0.f};

    for (int kk = 0; kk < K; kk += 32) {
#pragma unroll
        for (int i = 0; i < 2; ++i) {
            const int c   = i * 256 + tid;
            const int row = c >> 2;
            const int cg  = (c & 3) * 8;
            {
                const float* g = A + (size_t)(m0 + row) * K + kk + cg;
                float4 f0 = *(const float4*)g;
                float4 f1 = *(const float4*)(g + 4);
                bf16x8 u;
                u[0] = (__bf16)f0.x; u[1] = (__bf16)f0.y; u[2] = (__bf16)f0.z; u[3] = (__bf16)f0.w;
                u[4] = (__bf16)f1.x; u[5] = (__bf16)f1.y; u[6] = (__bf16)f1.z; u[7] = (__bf16)f1.w;
                *(bf16x8*)(&As[c * 8]) = u;
            }
            {
                const u16* g = W + (size_t)(n0 + row) * K + kk + cg;
                *(uint4*)(&Bs[c * 8]) = *(const uint4*)g;
            }
        }
        __syncthreads();

        bf16x8 af[4], bfr[4];
#pragma unroll
        for (int mi = 0; mi < 4; ++mi)
            af[mi] = *(const bf16x8*)(&As[(wr * 64 + mi * 16 + colg) * 32 + rowg * 8]);
#pragma unroll
        for (int ni = 0; ni < 4; ++ni)
            bfr[ni] = *(const bf16x8*)(&Bs[(wc * 64 + ni * 16 + colg) * 32 + rowg * 8]);
#pragma unroll
        for (int mi = 0; mi < 4; ++mi)
#pragma unroll
            for (int ni = 0; ni < 4; ++ni)
                acc[mi][ni] = mfma16(af[mi], bfr[ni], acc[mi][ni]);
        __syncthreads();
    }

    u16* Crm = (which == 0) ? Qp : Kp;
#pragma unroll
    for (int mi = 0; mi < 4; ++mi) {
#pragma unroll
        for (int ni = 0; ni < 4; ++ni) {
#pragma unroll
            for (int r = 0; r < 4; ++r) {
                const int row = m0 + wr * 64 + mi * 16 + rowg * 4 + r;
                const int col = n0 + wc * 64 + ni * 16 + colg;
                const float vv = acc[mi][ni][r];
                if (which < 2) {
                    Crm[(size_t)row * N + col] = f2bf(vv);
                } else {
                    const int b = row >> 11, t = row & 2047;
                    const int h = col >> 6,  d = col & 63;
                    Vt[((size_t)((b * 16 + h) * 64 + d) << 11) + t] = f2bf(vv);
                }
            }
        }
    }
}

// ---------------------------------------------------------------------------
// Output GEMM: out[m,n] = sum_k Cc[m,k]*Wo[n,k]. 64x128 tile -> 512 blocks.
// Cc bf16, Wo bf16, out fp32.
// ---------------------------------------------------------------------------
__global__ __launch_bounds__(256) void gemm_out(const u16* __restrict__ Ap,
                                                const u16* __restrict__ W,
                                                float* __restrict__ Cp) {
    constexpr int K = 1024, N = 1024;
    __shared__ u16 As[64 * 32];
    __shared__ u16 Bs[128 * 32];

    const int tid  = threadIdx.x;
    const int lane = tid & 63;
    const int w    = tid >> 6;
    const int wr = w >> 1, wc = w & 1;
    const int wg = (blockIdx.x & 7) * 64 + (blockIdx.x >> 3);
    const int m0 = (wg >> 3) * 64, n0 = (wg & 7) * 128;
    const int colg = lane & 15, rowg = lane >> 4;

    f32x4 acc[2][4];
#pragma unroll
    for (int i = 0; i < 2; ++i)
#pragma unroll
        for (int j = 0; j < 4; ++j) acc[i][j] = (f32x4){0.f, 0.f, 0.f, 0.f};

    for (int kk = 0; kk < K; kk += 32) {
        {
            const int c   = tid;            // 256 A chunks
            const int row = c >> 2;
            const int cg  = (c & 3) * 8;
            const u16* g  = Ap + (size_t)(m0 + row) * K + kk + cg;
            *(uint4*)(&As[c * 8]) = *(const uint4*)g;
        }
#pragma unroll
        for (int i = 0; i < 2; ++i) {
            const int c   = i * 256 + tid;  // 512 B chunks
            const int row = c >> 2;
            const int cg  = (c & 3) * 8;
            const u16* g  = W + (size_t)(n0 + row) * K + kk + cg;
            *(uint4*)(&Bs[c * 8]) = *(const uint4*)g;
        }
        __syncthreads();

        bf16x8 af[2], bfr[4];
#pragma unroll
        for (int mi = 0; mi < 2; ++mi)
            af[mi] = *(const bf16x8*)(&As[(wr * 32 + mi * 16 + colg) * 32 + rowg * 8]);
#pragma unroll
        for (int ni = 0; ni < 4; ++ni)
            bfr[ni] = *(const bf16x8*)(&Bs[(wc * 64 + ni * 16 + colg) * 32 + rowg * 8]);
#pragma unroll
        for (int mi = 0; mi < 2; ++mi)
#pragma unroll
            for (int ni = 0; ni < 4; ++ni)
                acc[mi][ni] = mfma16(af[mi], bfr[ni], acc[mi][ni]);
        __syncthreads();
    }

#pragma unroll
    for (int mi = 0; mi < 2; ++mi)
#pragma unroll
        for (int ni = 0; ni < 4; ++ni)
#pragma unroll
            for (int r = 0; r < 4; ++r) {
                const int row = m0 + wr * 32 + mi * 16 + rowg * 4 + r;
                const int col = n0 + wc * 64 + ni * 16 + colg;
                Cp[(size_t)row * N + col] = acc[mi][ni][r];
            }
}

// ---------------------------------------------------------------------------
// Flash attention, causal, KVBLK=128. One wave per block; wave owns q-stripes
// s and 127-s (16 rows each) -> balanced ~18 KV tiles per wave.
// ---------------------------------------------------------------------------
constexpr float CEXP = 0.18033688011112042f;  // 0.125 * log2(e)

__device__ __forceinline__ void attn_tile(int kvb, int q0, int colg, int rowg,
                                          const u16* __restrict__ Krow,
                                          const u16* __restrict__ Vb,
                                          bf16x8 qf0, bf16x8 qf1,
                                          float (&mm)[4], float (&ll)[4],
                                          f32x4 (&OO)[4], u16* PB) {
    constexpr int T = 2048, C = 1024;
    float pr[8][4];
#pragma unroll
    for (int sub = 0; sub < 8; ++sub) {
        const u16* kr = Krow + (size_t)(kvb + sub * 16 + colg) * C;
        bf16x8 kf0 = *(const bf16x8*)(kr + rowg * 8);
        bf16x8 kf1 = *(const bf16x8*)(kr + 32 + rowg * 8);
        f32x4 t = (f32x4){0.f, 0.f, 0.f, 0.f};
        t = mfma16(qf0, kf0, t);
        t = mfma16(qf1, kf1, t);
#pragma unroll
        for (int r = 0; r < 4; ++r) pr[sub][r] = t[r];
    }
    if (kvb + 127 > q0) {  // wave-uniform: tile touches the diagonal
#pragma unroll
        for (int sub = 0; sub < 8; ++sub)
#pragma unroll
            for (int r = 0; r < 4; ++r) {
                const int qg  = q0 + rowg * 4 + r;
                const int kvg = kvb + sub * 16 + colg;
                if (kvg > qg) pr[sub][r] = -1e30f;
            }
    }
#pragma unroll
    for (int r = 0; r < 4; ++r) {
        float pm = fmaxf(fmaxf(fmaxf(pr[0][r], pr[1][r]), fmaxf(pr[2][r], pr[3][r])),
                         fmaxf(fmaxf(pr[4][r], pr[5][r]), fmaxf(pr[6][r], pr[7][r])));
        pm = fmaxf(pm, __shfl_xor(pm, 1, 64));
        pm = fmaxf(pm, __shfl_xor(pm, 2, 64));
        pm = fmaxf(pm, __shfl_xor(pm, 4, 64));
        pm = fmaxf(pm, __shfl_xor(pm, 8, 64));
        const float mn = fmaxf(mm[r], pm);
        const float sc = __builtin_amdgcn_exp2f((mm[r] - mn) * CEXP);
        mm[r] = mn;
        float rs = 0.f;
#pragma unroll
        for (int sub = 0; sub < 8; ++sub) {
            const float e = __builtin_amdgcn_exp2f((pr[sub][r] - mn) * CEXP);
            pr[sub][r] = e;
            rs += e;
        }
        rs += __shfl_xor(rs, 1, 64);
        rs += __shfl_xor(rs, 2, 64);
        rs += __shfl_xor(rs, 4, 64);
        rs += __shfl_xor(rs, 8, 64);
        ll[r] = ll[r] * sc + rs;
#pragma unroll
        for (int g = 0; g < 4; ++g) OO[g][r] *= sc;
    }
    // P transpose through swizzled LDS: byte = (q*256 + kv*2) ^ ((q&7)<<4)
#pragma unroll
    for (int sub = 0; sub < 8; ++sub)
#pragma unroll
        for (int r = 0; r < 4; ++r) {
            const int qq = rowg * 4 + r;
            const int kv = sub * 16 + colg;
            const int wb = (qq * 256 + kv * 2) ^ ((qq & 7) << 4);
            *(u16*)((char*)PB + wb) = f2bf(pr[sub][r]);
        }
    bf16x8 pf[4];
#pragma unroll
    for (int kc = 0; kc < 4; ++kc) {
        const int rb = (colg * 256 + kc * 64 + rowg * 16) ^ ((colg & 7) << 4);
        pf[kc] = *(const bf16x8*)((char*)PB + rb);
    }
#pragma unroll
    for (int g = 0; g < 4; ++g) {
        const u16* vr = Vb + (size_t)(g * 16 + colg) * T + kvb;
#pragma unroll
        for (int kc = 0; kc < 4; ++kc) {
            bf16x8 vf = *(const bf16x8*)(vr + kc * 32 + rowg * 8);
            OO[g] = mfma16(pf[kc], vf, OO[g]);
        }
    }
}

__global__ __launch_bounds__(64) void attn_causal(const u16* __restrict__ Qp,
                                                  const u16* __restrict__ Kp,
                                                  const u16* __restrict__ Vt,
                                                  u16* __restrict__ concat) {
    constexpr int T = 2048, C = 1024;
    __shared__ __align__(16) u16 Pl[2][2048];

    const int lane = threadIdx.x;
    const int colg = lane & 15, rowg = lane >> 4;
    const int wg = (blockIdx.x & 7) * 256 + (blockIdx.x >> 3);  // XCD swizzle
    const int p  = wg & 63;
    const int bh = wg >> 6;
    const int b = bh >> 4, h = bh & 15;

    const int q0A = p * 16;
    const int q0B = (127 - p) * 16;

    const u16* Krow = Kp + (size_t)(b * T) * C + h * 64;
    const u16* Vb   = Vt + ((size_t)(b * 16 + h) * 64) * T;

    const u16* QA = Qp + (size_t)(b * T + q0A + colg) * C + h * 64;
    const u16* QB = Qp + (size_t)(b * T + q0B + colg) * C + h * 64;
    const bf16x8 qA0 = *(const bf16x8*)(QA + rowg * 8);
    const bf16x8 qA1 = *(const bf16x8*)(QA + 32 + rowg * 8);
    const bf16x8 qB0 = *(const bf16x8*)(QB + rowg * 8);
    const bf16x8 qB1 = *(const bf16x8*)(QB + 32 + rowg * 8);

    float mA[4], lA[4], mB[4], lB[4];
    f32x4 OA[4], OB[4];
#pragma unroll
    for (int r = 0; r < 4; ++r) { mA[r] = -INFINITY; lA[r] = 0.f; mB[r] = -INFINITY; lB[r] = 0.f; }
#pragma unroll
    for (int g = 0; g < 4; ++g) { OA[g] = (f32x4){0.f, 0.f, 0.f, 0.f}; OB[g] = (f32x4){0.f, 0.f, 0.f, 0.f}; }

    const int ntA = (q0A + 143) >> 7;
    const int ntB = (q0B + 143) >> 7;

    for (int kt = 0; kt < ntA; ++kt) {
        attn_tile(kt * 128, q0A, colg, rowg, Krow, Vb, qA0, qA1, mA, lA, OA, Pl[0]);
        attn_tile(kt * 128, q0B, colg, rowg, Krow, Vb, qB0, qB1, mB, lB, OB, Pl[1]);
    }
    for (int kt = ntA; kt < ntB; ++kt)
        attn_tile(kt * 128, q0B, colg, rowg, Krow, Vb, qB0, qB1, mB, lB, OB, Pl[1]);

#pragma unroll
    for (int r = 0; r < 4; ++r) {
        const float rcA = 1.f / lA[r];
        const float rcB = 1.f / lB[r];
        const size_t baseA = (size_t)(b * T + q0A + rowg * 4 + r) * C + h * 64;
        const size_t baseB = (size_t)(b * T + q0B + rowg * 4 + r) * C + h * 64;
#pragma unroll
        for (int g = 0; g < 4; ++g) {
            concat[baseA + g * 16 + colg] = f2bf(OA[g][r] * rcA);
            concat[baseB + g * 16 + colg] = f2bf(OB[g][r] * rcB);
        }
    }
}

// ---------------------------------------------------------------------------
extern "C" void kernel_launch(void* const* d_in, const int* in_sizes, int n_in,
                              void* d_out, int out_size, void* d_ws, size_t ws_size,
                              hipStream_t stream) {
    const float* q  = (const float*)d_in[0];
    const float* k  = (const float*)d_in[1];
    const float* v  = (const float*)d_in[2];
    const float* Wq = (const float*)d_in[3];
    const float* Wk = (const float*)d_in[4];
    const float* Wv = (const float*)d_in[5];
    const float* Wo = (const float*)d_in[6];
    float* out = (float*)d_out;

    constexpr size_t NELEM = (size_t)4096 * 1024;
    constexpr size_t WSZ   = (size_t)1 << 20;
    u16* Wb = (u16*)d_ws;
    u16* Qp = Wb + 4 * WSZ;
    u16* Kp = Qp + NELEM;
    u16* Vt = Kp + NELEM;
    u16* Cc = Vt + NELEM;

    cvt4<<<2048, 256, 0, stream>>>(Wq, Wk, Wv, Wo, Wb);

    gemm_qkv<<<768, 256, 0, stream>>>(q, k, v, Wb, Qp, Kp, Vt);

    attn_causal<<<2048, 64, 0, stream>>>(Qp, Kp, Vt, Cc);

    gemm_out<<<512, 256, 0, stream>>>(Cc, Wb + 3 * WSZ, out);
}

// Round 4
// 136.966 us; speedup vs baseline: 2.8261x; 1.4001x over previous
//
#include <hip/hip_runtime.h>
#include <hip/hip_bf16.h>

typedef __bf16 bf16x8 __attribute__((ext_vector_type(8)));
typedef float  f32x4  __attribute__((ext_vector_type(4)));
typedef unsigned short u16;

__device__ __forceinline__ u16 f2bf(float f) {
    __bf16 h = (__bf16)f;
    return __builtin_bit_cast(u16, h);
}

__device__ __forceinline__ f32x4 mfma16(bf16x8 a, bf16x8 b, f32x4 c) {
    return __builtin_amdgcn_mfma_f32_16x16x32_bf16(a, b, c, 0, 0, 0);
}

// ---------------------------------------------------------------------------
// Weight pre-conversion: 4 x [1M] fp32 -> bf16 concatenated.
// ---------------------------------------------------------------------------
__global__ __launch_bounds__(256) void cvt4(const float* __restrict__ W0,
                                            const float* __restrict__ W1,
                                            const float* __restrict__ W2,
                                            const float* __restrict__ W3,
                                            u16* __restrict__ dst) {
    const int t     = blockIdx.x * 256 + threadIdx.x;
    const int which = t >> 17;
    const int off   = (t & 0x1FFFF) * 8;
    const float* s  = (which == 0) ? W0 : (which == 1) ? W1 : (which == 2) ? W2 : W3;
    float4 f0 = *(const float4*)(s + off);
    float4 f1 = *(const float4*)(s + off + 4);
    bf16x8 u;
    u[0] = (__bf16)f0.x; u[1] = (__bf16)f0.y; u[2] = (__bf16)f0.z; u[3] = (__bf16)f0.w;
    u[4] = (__bf16)f1.x; u[5] = (__bf16)f1.y; u[6] = (__bf16)f1.z; u[7] = (__bf16)f1.w;
    *(bf16x8*)(dst + ((size_t)which << 20) + off) = u;
}

// ---------------------------------------------------------------------------
// Merged Q/K/V projection GEMM (128x128 tile, BK=32, 4 waves, 768 blocks).
// ---------------------------------------------------------------------------
__global__ __launch_bounds__(256) void gemm_qkv(const float* __restrict__ q,
                                                const float* __restrict__ k,
                                                const float* __restrict__ v,
                                                const u16* __restrict__ Wb,
                                                u16* __restrict__ Qp,
                                                u16* __restrict__ Kp,
                                                u16* __restrict__ Vt) {
    constexpr int K = 1024, N = 1024;
    __shared__ u16 As[128 * 32];
    __shared__ u16 Bs[128 * 32];

    const int tid  = threadIdx.x;
    const int lane = tid & 63;
    const int w    = tid >> 6;
    const int wr = w >> 1, wc = w & 1;
    const int wg    = (blockIdx.x & 7) * 96 + (blockIdx.x >> 3);  // XCD swizzle
    const int which = wg >> 8;
    const int inner = wg & 255;
    const int m0 = (inner >> 3) * 128, n0 = (inner & 7) * 128;
    const int colg = lane & 15, rowg = lane >> 4;

    const float* A = (which == 0) ? q : (which == 1) ? k : v;
    const u16*   W = Wb + ((size_t)which << 20);

    f32x4 acc[4][4];
#pragma unroll
    for (int i = 0; i < 4; ++i)
#pragma unroll
        for (int j = 0; j < 4; ++j) acc[i][j] = (f32x4){0.f, 0.f, 0.f, 0.f};

    for (int kk = 0; kk < K; kk += 32) {
#pragma unroll
        for (int i = 0; i < 2; ++i) {
            const int c   = i * 256 + tid;
            const int row = c >> 2;
            const int cg  = (c & 3) * 8;
            {
                const float* g = A + (size_t)(m0 + row) * K + kk + cg;
                float4 f0 = *(const float4*)g;
                float4 f1 = *(const float4*)(g + 4);
                bf16x8 u;
                u[0] = (__bf16)f0.x; u[1] = (__bf16)f0.y; u[2] = (__bf16)f0.z; u[3] = (__bf16)f0.w;
                u[4] = (__bf16)f1.x; u[5] = (__bf16)f1.y; u[6] = (__bf16)f1.z; u[7] = (__bf16)f1.w;
                *(bf16x8*)(&As[c * 8]) = u;
            }
            {
                const u16* g = W + (size_t)(n0 + row) * K + kk + cg;
                *(uint4*)(&Bs[c * 8]) = *(const uint4*)g;
            }
        }
        __syncthreads();

        bf16x8 af[4], bfr[4];
#pragma unroll
        for (int mi = 0; mi < 4; ++mi)
            af[mi] = *(const bf16x8*)(&As[(wr * 64 + mi * 16 + colg) * 32 + rowg * 8]);
#pragma unroll
        for (int ni = 0; ni < 4; ++ni)
            bfr[ni] = *(const bf16x8*)(&Bs[(wc * 64 + ni * 16 + colg) * 32 + rowg * 8]);
#pragma unroll
        for (int mi = 0; mi < 4; ++mi)
#pragma unroll
            for (int ni = 0; ni < 4; ++ni)
                acc[mi][ni] = mfma16(af[mi], bfr[ni], acc[mi][ni]);
        __syncthreads();
    }

    u16* Crm = (which == 0) ? Qp : Kp;
#pragma unroll
    for (int mi = 0; mi < 4; ++mi) {
#pragma unroll
        for (int ni = 0; ni < 4; ++ni) {
#pragma unroll
            for (int r = 0; r < 4; ++r) {
                const int row = m0 + wr * 64 + mi * 16 + rowg * 4 + r;
                const int col = n0 + wc * 64 + ni * 16 + colg;
                const float vv = acc[mi][ni][r];
                if (which < 2) {
                    Crm[(size_t)row * N + col] = f2bf(vv);
                } else {
                    const int b = row >> 11, t = row & 2047;
                    const int h = col >> 6,  d = col & 63;
                    Vt[((size_t)((b * 16 + h) * 64 + d) << 11) + t] = f2bf(vv);
                }
            }
        }
    }
}

// ---------------------------------------------------------------------------
// Output GEMM: out[m,n] = sum_k Cc[m,k]*Wo[n,k]. 64x128 tile -> 512 blocks.
// ---------------------------------------------------------------------------
__global__ __launch_bounds__(256) void gemm_out(const u16* __restrict__ Ap,
                                                const u16* __restrict__ W,
                                                float* __restrict__ Cp) {
    constexpr int K = 1024, N = 1024;
    __shared__ u16 As[64 * 32];
    __shared__ u16 Bs[128 * 32];

    const int tid  = threadIdx.x;
    const int lane = tid & 63;
    const int w    = tid >> 6;
    const int wr = w >> 1, wc = w & 1;
    const int wg = (blockIdx.x & 7) * 64 + (blockIdx.x >> 3);
    const int m0 = (wg >> 3) * 64, n0 = (wg & 7) * 128;
    const int colg = lane & 15, rowg = lane >> 4;

    f32x4 acc[2][4];
#pragma unroll
    for (int i = 0; i < 2; ++i)
#pragma unroll
        for (int j = 0; j < 4; ++j) acc[i][j] = (f32x4){0.f, 0.f, 0.f, 0.f};

    for (int kk = 0; kk < K; kk += 32) {
        {
            const int c   = tid;
            const int row = c >> 2;
            const int cg  = (c & 3) * 8;
            const u16* g  = Ap + (size_t)(m0 + row) * K + kk + cg;
            *(uint4*)(&As[c * 8]) = *(const uint4*)g;
        }
#pragma unroll
        for (int i = 0; i < 2; ++i) {
            const int c   = i * 256 + tid;
            const int row = c >> 2;
            const int cg  = (c & 3) * 8;
            const u16* g  = W + (size_t)(n0 + row) * K + kk + cg;
            *(uint4*)(&Bs[c * 8]) = *(const uint4*)g;
        }
        __syncthreads();

        bf16x8 af[2], bfr[4];
#pragma unroll
        for (int mi = 0; mi < 2; ++mi)
            af[mi] = *(const bf16x8*)(&As[(wr * 32 + mi * 16 + colg) * 32 + rowg * 8]);
#pragma unroll
        for (int ni = 0; ni < 4; ++ni)
            bfr[ni] = *(const bf16x8*)(&Bs[(wc * 64 + ni * 16 + colg) * 32 + rowg * 8]);
#pragma unroll
        for (int mi = 0; mi < 2; ++mi)
#pragma unroll
            for (int ni = 0; ni < 4; ++ni)
                acc[mi][ni] = mfma16(af[mi], bfr[ni], acc[mi][ni]);
        __syncthreads();
    }

#pragma unroll
    for (int mi = 0; mi < 2; ++mi)
#pragma unroll
        for (int ni = 0; ni < 4; ++ni)
#pragma unroll
            for (int r = 0; r < 4; ++r) {
                const int row = m0 + wr * 32 + mi * 16 + rowg * 4 + r;
                const int col = n0 + wc * 64 + ni * 16 + colg;
                Cp[(size_t)row * N + col] = acc[mi][ni][r];
            }
}

// ---------------------------------------------------------------------------
// Flash attention v3: 4-wave blocks, block-staged K/V in swizzled LDS,
// swapped QK^T (lane-local softmax), defer-rescale.
// Each wave owns one 16-row q-stripe; block = 4 consecutive stripes.
// Grid: 1024 blocks, descending-work order, XCD-grouped (4 bh / XCD).
// ---------------------------------------------------------------------------
constexpr float CEXP = 0.18033688011112042f;  // 0.125 * log2(e)

__global__ __launch_bounds__(256) void attn_causal(const u16* __restrict__ Qp,
                                                   const u16* __restrict__ Kp,
                                                   const u16* __restrict__ Vt,
                                                   u16* __restrict__ concat) {
    constexpr int T = 2048, C = 1024;
    __shared__ __align__(16) u16 Ks[128 * 64];   // [kv][d]   rows 128B, swz (kv&7)<<4
    __shared__ __align__(16) u16 Vs[64 * 128];   // [d][kv]   rows 256B, swz (d&7)<<4
    __shared__ __align__(16) u16 Pl[4][2048];    // per-wave P [q16][kv128], swz (q&7)<<4

    const int tid  = threadIdx.x;
    const int lane = tid & 63;
    const int w    = tid >> 6;
    const int colg = lane & 15, rowg = lane >> 4;

    // block mapping: xcd-grouped, descending work
    const int idx = blockIdx.x;
    const int xcd = idx & 7;
    const int i1  = idx >> 3;              // 0..127
    const int bh  = xcd * 4 + (i1 & 3);
    const int qg  = 31 - (i1 >> 2);        // stripe group, big work first
    const int b = bh >> 4, h = bh & 15;

    const int q0 = (qg * 4 + w) * 16;      // this wave's q-stripe
    const int nt    = (q0 + 143) >> 7;                 // my KV tiles
    const int ktmax = ((qg * 4 + 3) * 16 + 143) >> 7;  // block max

    const char* Kg = (const char*)(Kp + (size_t)(b * T) * C + h * 64);  // row stride 2048B
    const char* Vg = (const char*)(Vt + ((size_t)(b * 16 + h) * 64) * T);  // row stride 4096B
    char* Ksb = (char*)Ks;
    char* Vsb = (char*)Vs;
    char* Pw  = (char*)&Pl[w][0];

    // Q fragment (B-operand of swapped QK): lane holds Q[q0+colg][rowg*8..]
    const u16* Qb = Qp + (size_t)(b * T + q0 + colg) * C + h * 64;
    const bf16x8 qf0 = *(const bf16x8*)(Qb + rowg * 8);
    const bf16x8 qf1 = *(const bf16x8*)(Qb + 32 + rowg * 8);

    float mm = -1e30f, ll = 0.f;
    f32x4 O[4];
#pragma unroll
    for (int g = 0; g < 4; ++g) O[g] = (f32x4){0.f, 0.f, 0.f, 0.f};

    const int sw = (colg & 7) << 4;

    for (int kt = 0; kt < ktmax; ++kt) {
        const int kvb = kt * 128;
        // ---- stage K (128x64) and V (64x128) tiles into swizzled LDS ----
        uint4 kst[4], vst[4];
#pragma unroll
        for (int i2 = 0; i2 < 4; ++i2) {
            const int s  = i2 * 4096 + tid * 16;
            const int kv = s >> 7, ir = s & 127;
            kst[i2] = *(const uint4*)(Kg + (size_t)(kvb + kv) * 2048 + ir);
            const int d = s >> 8, irv = s & 255;
            vst[i2] = *(const uint4*)(Vg + (size_t)d * 4096 + (size_t)kvb * 2 + irv);
        }
#pragma unroll
        for (int i2 = 0; i2 < 4; ++i2) {
            const int s  = i2 * 4096 + tid * 16;
            const int kv = s >> 7;
            *(uint4*)(Ksb + (s ^ ((kv & 7) << 4))) = kst[i2];
            const int d = s >> 8;
            *(uint4*)(Vsb + (s ^ ((d & 7) << 4))) = vst[i2];
        }
        __syncthreads();

        if (kt < nt) {
            // ---- swapped QK^T: lane holds S[q=q0+colg][32 kv values] ----
            float pr[8][4];
#pragma unroll
            for (int sub = 0; sub < 8; ++sub) {
                const int kb = (sub * 16 + colg) * 128 + rowg * 16;
                bf16x8 kf0 = *(const bf16x8*)(Ksb + (kb ^ sw));
                bf16x8 kf1 = *(const bf16x8*)(Ksb + ((kb + 64) ^ sw));
                f32x4 t = (f32x4){0.f, 0.f, 0.f, 0.f};
                t = mfma16(kf0, qf0, t);
                t = mfma16(kf1, qf1, t);
#pragma unroll
                for (int r = 0; r < 4; ++r) pr[sub][r] = t[r];
            }
            if (kvb + 127 > q0) {  // diagonal tile only
#pragma unroll
                for (int sub = 0; sub < 8; ++sub)
#pragma unroll
                    for (int r = 0; r < 4; ++r)
                        if (kvb + sub * 16 + rowg * 4 + r > q0 + colg) pr[sub][r] = -1e30f;
            }
            // ---- in-lane max + 2 shuffles ----
            float mx[8];
#pragma unroll
            for (int sub = 0; sub < 8; ++sub)
                mx[sub] = fmaxf(fmaxf(pr[sub][0], pr[sub][1]), fmaxf(pr[sub][2], pr[sub][3]));
            float pm = fmaxf(fmaxf(fmaxf(mx[0], mx[1]), fmaxf(mx[2], mx[3])),
                             fmaxf(fmaxf(mx[4], mx[5]), fmaxf(mx[6], mx[7])));
            pm = fmaxf(pm, __shfl_xor(pm, 16, 64));
            pm = fmaxf(pm, __shfl_xor(pm, 32, 64));
            // ---- defer-rescale ----
            if (__any(pm > mm + 40.f)) {
                const float mn = fmaxf(mm, pm);
                const float sc = __builtin_amdgcn_exp2f((mm - mn) * CEXP);
                mm = mn;
                ll *= sc;
#pragma unroll
                for (int r = 0; r < 4; ++r) {
                    const float scr = __shfl(sc, (lane & 48) + rowg * 4 + r, 64);
#pragma unroll
                    for (int g = 0; g < 4; ++g) O[g][r] *= scr;
                }
            }
            // ---- exp + in-lane sum + 2 shuffles ----
            float rs = 0.f;
#pragma unroll
            for (int sub = 0; sub < 8; ++sub) {
                const float e0 = __builtin_amdgcn_exp2f((pr[sub][0] - mm) * CEXP);
                const float e1 = __builtin_amdgcn_exp2f((pr[sub][1] - mm) * CEXP);
                const float e2 = __builtin_amdgcn_exp2f((pr[sub][2] - mm) * CEXP);
                const float e3 = __builtin_amdgcn_exp2f((pr[sub][3] - mm) * CEXP);
                pr[sub][0] = e0; pr[sub][1] = e1; pr[sub][2] = e2; pr[sub][3] = e3;
                rs += (e0 + e1) + (e2 + e3);
            }
            rs += __shfl_xor(rs, 16, 64);
            rs += __shfl_xor(rs, 32, 64);
            ll += rs;
            // ---- P -> LDS (b64 packed, swizzled) ----
#pragma unroll
            for (int sub = 0; sub < 8; ++sub) {
                uint2 pk;
                pk.x = (unsigned)f2bf(pr[sub][0]) | ((unsigned)f2bf(pr[sub][1]) << 16);
                pk.y = (unsigned)f2bf(pr[sub][2]) | ((unsigned)f2bf(pr[sub][3]) << 16);
                const int wb = (colg * 256 + sub * 32 + rowg * 8) ^ sw;
                *(uint2*)(Pw + wb) = pk;
            }
            // ---- PV from LDS ----
            bf16x8 pf[4];
#pragma unroll
            for (int kc = 0; kc < 4; ++kc)
                pf[kc] = *(const bf16x8*)(Pw + ((colg * 256 + kc * 64 + rowg * 16) ^ sw));
#pragma unroll
            for (int g = 0; g < 4; ++g) {
                const int vb0 = (g * 16 + colg) * 256 + rowg * 16;
#pragma unroll
                for (int kc = 0; kc < 4; ++kc) {
                    bf16x8 vf = *(const bf16x8*)(Vsb + ((vb0 + kc * 64) ^ sw));
                    O[g] = mfma16(pf[kc], vf, O[g]);
                }
            }
        }
        __syncthreads();
    }

    // ---- epilogue: broadcast l, divide, store ----
#pragma unroll
    for (int r = 0; r < 4; ++r) {
        const float lr = __shfl(ll, (lane & 48) + rowg * 4 + r, 64);
        const float rc = 1.f / lr;
        const size_t base = (size_t)(b * T + q0 + rowg * 4 + r) * C + h * 64;
#pragma unroll
        for (int g = 0; g < 4; ++g)
            concat[base + g * 16 + colg] = f2bf(O[g][r] * rc);
    }
}

// ---------------------------------------------------------------------------
extern "C" void kernel_launch(void* const* d_in, const int* in_sizes, int n_in,
                              void* d_out, int out_size, void* d_ws, size_t ws_size,
                              hipStream_t stream) {
    const float* q  = (const float*)d_in[0];
    const float* k  = (const float*)d_in[1];
    const float* v  = (const float*)d_in[2];
    const float* Wq = (const float*)d_in[3];
    const float* Wk = (const float*)d_in[4];
    const float* Wv = (const float*)d_in[5];
    const float* Wo = (const float*)d_in[6];
    float* out = (float*)d_out;

    constexpr size_t NELEM = (size_t)4096 * 1024;
    constexpr size_t WSZ   = (size_t)1 << 20;
    u16* Wb = (u16*)d_ws;
    u16* Qp = Wb + 4 * WSZ;
    u16* Kp = Qp + NELEM;
    u16* Vt = Kp + NELEM;
    u16* Cc = Vt + NELEM;

    cvt4<<<2048, 256, 0, stream>>>(Wq, Wk, Wv, Wo, Wb);

    gemm_qkv<<<768, 256, 0, stream>>>(q, k, v, Wb, Qp, Kp, Vt);

    attn_causal<<<1024, 256, 0, stream>>>(Qp, Kp, Vt, Cc);

    gemm_out<<<512, 256, 0, stream>>>(Cc, Wb + 3 * WSZ, out);
}